// Round 1
// baseline (611.375 us; speedup 1.0000x reference)
//
#include <hip/hip_runtime.h>

#define NN 50000
#define NE 800000
#define F_IN 8
#define H 128

__global__ void k_zero2(int* __restrict__ a, int* __restrict__ b, int n) {
    int i = blockIdx.x * blockDim.x + threadIdx.x;
    if (i < n) { a[i] = 0; b[i] = 0; }
}

__global__ void k_indeg(const int* __restrict__ dst, int* __restrict__ indeg) {
    int i = blockIdx.x * blockDim.x + threadIdx.x;
    if (i < NE) atomicAdd(&indeg[dst[i]], 1);
}

__global__ void k_dinv(const int* __restrict__ indeg, float* __restrict__ dinv) {
    int i = blockIdx.x * blockDim.x + threadIdx.x;
    if (i < NN) dinv[i] = rsqrtf((float)(indeg[i] + 1));
}

__global__ __launch_bounds__(1024) void k_scan(const int* __restrict__ indeg,
                                               int* __restrict__ rowstart) {
    __shared__ int sums[1024];
    int t = threadIdx.x;
    const int CH = (NN + 1023) / 1024;  // 49
    int lo = t * CH;
    int hi = lo + CH; if (hi > NN) hi = NN;
    if (lo > NN) lo = NN;
    int s = 0;
    for (int i = lo; i < hi; ++i) s += indeg[i];
    sums[t] = s;
    __syncthreads();
    for (int off = 1; off < 1024; off <<= 1) {
        int v = (t >= off) ? sums[t - off] : 0;
        __syncthreads();
        sums[t] += v;
        __syncthreads();
    }
    int run = (t == 0) ? 0 : sums[t - 1];
    for (int i = lo; i < hi; ++i) { rowstart[i] = run; run += indeg[i]; }
    if (t == 1023) rowstart[NN] = sums[1023];
}

__global__ void k_fill(const int* __restrict__ src, const int* __restrict__ dst,
                       const int* __restrict__ rowstart, int* __restrict__ cursor,
                       int* __restrict__ csr) {
    int i = blockIdx.x * blockDim.x + threadIdx.x;
    if (i < NE) {
        int d = dst[i];
        int pos = atomicAdd(&cursor[d], 1);
        csr[rowstart[d] + pos] = src[i];
    }
}

// h[n][j] = sum_k x[n][k] * W1[k][j]   (2 nodes per 256-thread block)
__global__ __launch_bounds__(256) void k_xw1(const float* __restrict__ x,
                                             const float* __restrict__ W1,
                                             float* __restrict__ h) {
    int t = threadIdx.x;
    int n = blockIdx.x * 2 + (t >> 7);
    int j = t & 127;
    const float* xr = x + n * F_IN;
    float acc = 0.f;
#pragma unroll
    for (int k = 0; k < F_IN; ++k) acc += xr[k] * W1[k * H + j];
    h[n * H + j] = acc;
}

// p[n] = relu( h[n]*dinv[n]^2 + sum_{incoming s} h[s]*dinv[s]*dinv[n] + bias )
__global__ __launch_bounds__(128) void k_agg(const float* __restrict__ h,
                                             const float* __restrict__ dinv,
                                             const int* __restrict__ rowstart,
                                             const int* __restrict__ csr,
                                             const float* __restrict__ bias,
                                             float* __restrict__ p) {
    int n = blockIdx.x, t = threadIdx.x;
    float dn = dinv[n];
    float acc = h[n * H + t] * (dn * dn);
    int lo = rowstart[n], hi = rowstart[n + 1];
    for (int i = lo; i < hi; ++i) {
        int s = csr[i];
        acc += h[s * H + t] * (dinv[s] * dn);
    }
    p[n * H + t] = fmaxf(acc + bias[t], 0.f);
}

// Y[NNpad rows used: NN][128] = X[.,128] @ W[128][128]; 32 nodes / 256-thread block.
// W staged in LDS (64KB); X read via L1 (2-address broadcast per instr, tile stays hot).
#define GNT 32
__global__ __launch_bounds__(256) void k_gemm128(const float* __restrict__ X,
                                                 const float* __restrict__ W,
                                                 float* __restrict__ Y) {
    __shared__ float Ws[128 * 128];
    int t = threadIdx.x;
    int base = blockIdx.x * GNT;
    for (int i = t * 4; i < 128 * 128; i += 256 * 4)
        *(float4*)&Ws[i] = *(const float4*)&W[i];
    __syncthreads();
    int jt = (t & 31) * 4;        // 4 output cols
    int nt = (t >> 5) * 4;        // 4 local rows
    float4 a0 = {0,0,0,0}, a1 = {0,0,0,0}, a2 = {0,0,0,0}, a3 = {0,0,0,0};
    const float* x0 = X + (base + nt + 0) * H;
    const float* x1 = X + (base + nt + 1) * H;
    const float* x2 = X + (base + nt + 2) * H;
    const float* x3 = X + (base + nt + 3) * H;
    for (int k = 0; k < 128; ++k) {
        float4 w = *(float4*)&Ws[k * 128 + jt];
        float v0 = x0[k], v1 = x1[k], v2 = x2[k], v3 = x3[k];
        a0.x += v0 * w.x; a0.y += v0 * w.y; a0.z += v0 * w.z; a0.w += v0 * w.w;
        a1.x += v1 * w.x; a1.y += v1 * w.y; a1.z += v1 * w.z; a1.w += v1 * w.w;
        a2.x += v2 * w.x; a2.y += v2 * w.y; a2.z += v2 * w.z; a2.w += v2 * w.w;
        a3.x += v3 * w.x; a3.y += v3 * w.y; a3.z += v3 * w.z; a3.w += v3 * w.w;
    }
    if (base + nt + 0 < NN) *(float4*)&Y[(base + nt + 0) * H + jt] = a0;
    if (base + nt + 1 < NN) *(float4*)&Y[(base + nt + 1) * H + jt] = a1;
    if (base + nt + 2 < NN) *(float4*)&Y[(base + nt + 2) * H + jt] = a2;
    if (base + nt + 3 < NN) *(float4*)&Y[(base + nt + 3) * H + jt] = a3;
}

// Fused edge stage: h = relu(u[src] + v[dst] + bl1); out = relu(h @ Wl2 + bl2).
// 16 lanes per edge (4 edges/wave, 16 edges/block). Lane owns j in
// {l16*4..+3} and {64+l16*4..+3} -> fully coalesced 256B row segments.
__global__ __launch_bounds__(256) void k_edge(const int* __restrict__ src,
                                              const int* __restrict__ dst,
                                              const float* __restrict__ u,
                                              const float* __restrict__ v,
                                              const float* __restrict__ bl1,
                                              const float* __restrict__ Wl2,
                                              const float* __restrict__ bl2,
                                              float* __restrict__ out) {
    int t = threadIdx.x;
    int lane = t & 63;
    int sub = lane >> 4;    // edge within wave
    int l16 = lane & 15;
    int e = blockIdx.x * 16 + (t >> 6) * 4 + sub;   // NE divisible by 16
    int s = src[e], d = dst[e];
    const float* ur = u + s * H;
    const float* vr = v + d * H;
    float4 ua = *(const float4*)(ur + l16 * 4);
    float4 ub = *(const float4*)(ur + 64 + l16 * 4);
    float4 va = *(const float4*)(vr + l16 * 4);
    float4 vb = *(const float4*)(vr + 64 + l16 * 4);
    float4 ba = *(const float4*)(bl1 + l16 * 4);
    float4 bb = *(const float4*)(bl1 + 64 + l16 * 4);
    float4 ha, hb;
    ha.x = fmaxf(ua.x + va.x + ba.x, 0.f);
    ha.y = fmaxf(ua.y + va.y + ba.y, 0.f);
    ha.z = fmaxf(ua.z + va.z + ba.z, 0.f);
    ha.w = fmaxf(ua.w + va.w + ba.w, 0.f);
    hb.x = fmaxf(ub.x + vb.x + bb.x, 0.f);
    hb.y = fmaxf(ub.y + vb.y + bb.y, 0.f);
    hb.z = fmaxf(ub.z + vb.z + bb.z, 0.f);
    hb.w = fmaxf(ub.w + vb.w + bb.w, 0.f);
    // Wl2 is [128][2] row-major: Wl2[j*2+c]
    float4 wa0 = *(const float4*)(Wl2 + l16 * 8);
    float4 wa1 = *(const float4*)(Wl2 + l16 * 8 + 4);
    float4 wb0 = *(const float4*)(Wl2 + 128 + l16 * 8);
    float4 wb1 = *(const float4*)(Wl2 + 128 + l16 * 8 + 4);
    float p0 = ha.x * wa0.x + ha.y * wa0.z + ha.z * wa1.x + ha.w * wa1.z
             + hb.x * wb0.x + hb.y * wb0.z + hb.z * wb1.x + hb.w * wb1.z;
    float p1 = ha.x * wa0.y + ha.y * wa0.w + ha.z * wa1.y + ha.w * wa1.w
             + hb.x * wb0.y + hb.y * wb0.w + hb.z * wb1.y + hb.w * wb1.w;
#pragma unroll
    for (int m = 1; m < 16; m <<= 1) {
        p0 += __shfl_xor(p0, m, 64);
        p1 += __shfl_xor(p1, m, 64);
    }
    if (l16 == 0) {
        float2 o;
        o.x = fmaxf(p0 + bl2[0], 0.f);
        o.y = fmaxf(p1 + bl2[1], 0.f);
        *(float2*)(out + (size_t)e * 2) = o;
    }
}

extern "C" void kernel_launch(void* const* d_in, const int* in_sizes, int n_in,
                              void* d_out, int out_size, void* d_ws, size_t ws_size,
                              hipStream_t stream) {
    const float* x   = (const float*)d_in[0];
    const float* W1  = (const float*)d_in[1];
    const float* b1  = (const float*)d_in[2];
    const float* W2  = (const float*)d_in[3];
    const float* b2  = (const float*)d_in[4];
    const float* Wl1 = (const float*)d_in[5];
    const float* bl1 = (const float*)d_in[6];
    const float* Wl2 = (const float*)d_in[7];
    const float* bl2 = (const float*)d_in[8];
    const int*   ei  = (const int*)d_in[9];
    const int* src = ei;
    const int* dst = ei + NE;
    float* out = (float*)d_out;

    char* ws = (char*)d_ws;
    size_t off = 0;
    auto alloc = [&](size_t bytes) -> void* {
        void* p = ws + off;
        off = (off + bytes + 255) & ~(size_t)255;
        return p;
    };
    int*   indeg    = (int*)alloc(NN * 4);
    float* dinv     = (float*)alloc(NN * 4);
    int*   rowstart = (int*)alloc((NN + 1) * 4);
    int*   cursor   = (int*)alloc(NN * 4);
    int*   csr      = (int*)alloc(NE * 4);
    const size_t NP = 50048;  // padded rows (gemm tile over-read safety)
    float* A = (float*)alloc(NP * H * 4);
    float* B = (float*)alloc(NP * H * 4);
    float* C = (float*)alloc(NP * H * 4);

    k_zero2<<<(NN + 255) / 256, 256, 0, stream>>>(indeg, cursor, NN);
    k_indeg<<<(NE + 255) / 256, 256, 0, stream>>>(dst, indeg);
    k_dinv<<<(NN + 255) / 256, 256, 0, stream>>>(indeg, dinv);
    k_scan<<<1, 1024, 0, stream>>>(indeg, rowstart);
    k_fill<<<(NE + 255) / 256, 256, 0, stream>>>(src, dst, rowstart, cursor, csr);

    k_xw1<<<NN / 2, 256, 0, stream>>>(x, W1, A);                       // h1 = A
    k_agg<<<NN, 128, 0, stream>>>(A, dinv, rowstart, csr, b1, B);      // p1 = B
    k_gemm128<<<(NN + GNT - 1) / GNT, 256, 0, stream>>>(B, W2, A);     // h2 = A
    k_agg<<<NN, 128, 0, stream>>>(A, dinv, rowstart, csr, b2, C);      // p2 = C
    k_gemm128<<<(NN + GNT - 1) / GNT, 256, 0, stream>>>(C, Wl1, A);            // u = A
    k_gemm128<<<(NN + GNT - 1) / GNT, 256, 0, stream>>>(C, Wl1 + 128 * H, B);  // v = B
    k_edge<<<NE / 16, 256, 0, stream>>>(src, dst, A, B, bl1, Wl2, bl2, out);
}

// Round 2
// 465.255 us; speedup vs baseline: 1.3141x; 1.3141x over previous
//
#include <hip/hip_runtime.h>

#define NN 50000
#define NE 800000
#define F_IN 8
#define H 128

typedef unsigned int uint;
typedef unsigned short ushort;

__device__ __forceinline__ ushort f2bf(float f) {
    uint u = __float_as_uint(f);
    uint r = (u + 0x7fffu + ((u >> 16) & 1u)) >> 16;
    return (ushort)r;
}
__device__ __forceinline__ float bflo(uint u) { return __uint_as_float(u << 16); }
__device__ __forceinline__ float bfhi(uint u) { return __uint_as_float(u & 0xffff0000u); }

struct ushort4x { ushort a, b, c, d; };

__global__ void k_zero2(int* __restrict__ a, int* __restrict__ b, int n) {
    int i = blockIdx.x * blockDim.x + threadIdx.x;
    if (i < n) { a[i] = 0; b[i] = 0; }
}

__global__ void k_indeg(const int* __restrict__ dst, int* __restrict__ indeg) {
    int i = blockIdx.x * blockDim.x + threadIdx.x;
    if (i < NE) atomicAdd(&indeg[dst[i]], 1);
}

__global__ void k_dinv(const int* __restrict__ indeg, float* __restrict__ dinv) {
    int i = blockIdx.x * blockDim.x + threadIdx.x;
    if (i < NN) dinv[i] = rsqrtf((float)(indeg[i] + 1));
}

__global__ __launch_bounds__(1024) void k_scan(const int* __restrict__ indeg,
                                               int* __restrict__ rowstart) {
    __shared__ int sums[1024];
    int t = threadIdx.x;
    const int CH = (NN + 1023) / 1024;  // 49
    int lo = t * CH;
    int hi = lo + CH; if (hi > NN) hi = NN;
    if (lo > NN) lo = NN;
    int s = 0;
    for (int i = lo; i < hi; ++i) s += indeg[i];
    sums[t] = s;
    __syncthreads();
    for (int off = 1; off < 1024; off <<= 1) {
        int v = (t >= off) ? sums[t - off] : 0;
        __syncthreads();
        sums[t] += v;
        __syncthreads();
    }
    int run = (t == 0) ? 0 : sums[t - 1];
    for (int i = lo; i < hi; ++i) { rowstart[i] = run; run += indeg[i]; }
    if (t == 1023) rowstart[NN] = sums[1023];
}

// CSR entries carry (src, edge_id) so the edge stage can run dst-sorted.
__global__ void k_fill(const int* __restrict__ src, const int* __restrict__ dst,
                       const int* __restrict__ rowstart, int* __restrict__ cursor,
                       int2* __restrict__ csr2) {
    int i = blockIdx.x * blockDim.x + threadIdx.x;
    if (i < NE) {
        int d = dst[i];
        int pos = atomicAdd(&cursor[d], 1);
        csr2[rowstart[d] + pos] = make_int2(src[i], i);
    }
}

// h[n][j] = sum_k x[n][k] * W1[k][j], bf16 output  (2 nodes / 256-thread block)
__global__ __launch_bounds__(256) void k_xw1(const float* __restrict__ x,
                                             const float* __restrict__ W1,
                                             ushort* __restrict__ h) {
    int t = threadIdx.x;
    int n = blockIdx.x * 2 + (t >> 7);
    int j = t & 127;
    const float* xr = x + n * F_IN;
    float acc = 0.f;
#pragma unroll
    for (int k = 0; k < F_IN; ++k) acc += xr[k] * W1[k * H + j];
    h[n * H + j] = f2bf(acc);
}

// p[n] = relu( h[n]*dinv[n]^2 + sum_{incoming s} h[s]*dinv[s]*dinv[n] + bias )
// h is bf16; 64 threads/block, lane t owns columns (2t, 2t+1) via one uint load.
__global__ __launch_bounds__(64) void k_agg(const ushort* __restrict__ h,
                                            const float* __restrict__ dinv,
                                            const int* __restrict__ rowstart,
                                            const int2* __restrict__ csr2,
                                            const float* __restrict__ bias,
                                            float* __restrict__ p) {
    int n = blockIdx.x, t = threadIdx.x;
    float dn = dinv[n];
    uint us = ((const uint*)(h + (size_t)n * H))[t];
    float w0 = dn * dn;
    float ax = bflo(us) * w0;
    float ay = bfhi(us) * w0;
    int lo = rowstart[n], hi = rowstart[n + 1];
    for (int i = lo; i < hi; ++i) {
        int2 e = csr2[i];
        int s = e.x;
        uint uu = ((const uint*)(h + (size_t)s * H))[t];
        float w = dinv[s] * dn;
        ax += bflo(uu) * w;
        ay += bfhi(uu) * w;
    }
    float2 bb = ((const float2*)bias)[t];
    float2 r;
    r.x = fmaxf(ax + bb.x, 0.f);
    r.y = fmaxf(ay + bb.y, 0.f);
    ((float2*)p)[(size_t)n * (H / 2) + t] = r;
}

// Y[.,128](bf16) = X[.,128](f32) @ W[128][128]; 32 rows / 256-thread block.
#define GNT 32
__global__ __launch_bounds__(256) void k_gemm128(const float* __restrict__ X,
                                                 const float* __restrict__ W,
                                                 ushort* __restrict__ Y) {
    __shared__ float Ws[128 * 128];
    int t = threadIdx.x;
    int base = blockIdx.x * GNT;
    for (int i = t * 4; i < 128 * 128; i += 256 * 4)
        *(float4*)&Ws[i] = *(const float4*)&W[i];
    __syncthreads();
    int jt = (t & 31) * 4;        // 4 output cols
    int nt = (t >> 5) * 4;        // 4 local rows
    float4 a0 = {0,0,0,0}, a1 = {0,0,0,0}, a2 = {0,0,0,0}, a3 = {0,0,0,0};
    const float* x0 = X + (size_t)(base + nt + 0) * H;
    const float* x1 = X + (size_t)(base + nt + 1) * H;
    const float* x2 = X + (size_t)(base + nt + 2) * H;
    const float* x3 = X + (size_t)(base + nt + 3) * H;
    for (int k0 = 0; k0 < 128; k0 += 4) {
        float4 xv0 = *(const float4*)(x0 + k0);
        float4 xv1 = *(const float4*)(x1 + k0);
        float4 xv2 = *(const float4*)(x2 + k0);
        float4 xv3 = *(const float4*)(x3 + k0);
#pragma unroll
        for (int kk = 0; kk < 4; ++kk) {
            float4 w = *(float4*)&Ws[(k0 + kk) * 128 + jt];
            float v0 = (&xv0.x)[kk], v1 = (&xv1.x)[kk], v2 = (&xv2.x)[kk], v3 = (&xv3.x)[kk];
            a0.x += v0 * w.x; a0.y += v0 * w.y; a0.z += v0 * w.z; a0.w += v0 * w.w;
            a1.x += v1 * w.x; a1.y += v1 * w.y; a1.z += v1 * w.z; a1.w += v1 * w.w;
            a2.x += v2 * w.x; a2.y += v2 * w.y; a2.z += v2 * w.z; a2.w += v2 * w.w;
            a3.x += v3 * w.x; a3.y += v3 * w.y; a3.z += v3 * w.z; a3.w += v3 * w.w;
        }
    }
    ushort4x o;
    if (base + nt + 0 < NN) {
        o.a = f2bf(a0.x); o.b = f2bf(a0.y); o.c = f2bf(a0.z); o.d = f2bf(a0.w);
        *(ushort4x*)&Y[(size_t)(base + nt + 0) * H + jt] = o;
    }
    if (base + nt + 1 < NN) {
        o.a = f2bf(a1.x); o.b = f2bf(a1.y); o.c = f2bf(a1.z); o.d = f2bf(a1.w);
        *(ushort4x*)&Y[(size_t)(base + nt + 1) * H + jt] = o;
    }
    if (base + nt + 2 < NN) {
        o.a = f2bf(a2.x); o.b = f2bf(a2.y); o.c = f2bf(a2.z); o.d = f2bf(a2.w);
        *(ushort4x*)&Y[(size_t)(base + nt + 2) * H + jt] = o;
    }
    if (base + nt + 3 < NN) {
        o.a = f2bf(a3.x); o.b = f2bf(a3.y); o.c = f2bf(a3.z); o.d = f2bf(a3.w);
        *(ushort4x*)&Y[(size_t)(base + nt + 3) * H + jt] = o;
    }
}

// Dst-sorted fused edge stage. One wave per destination node.
// v[d]+bl1 held in regs (loaded once); loop over incoming edges, 16 lanes/edge,
// gather u[src] (bf16, 256B/row), h=relu(u+v+b), out=relu(h@Wl2+bl2) at out[eid].
__global__ __launch_bounds__(64) void k_edge(const int* __restrict__ rowstart,
                                             const int2* __restrict__ csr2,
                                             const ushort* __restrict__ u,
                                             const ushort* __restrict__ v,
                                             const float* __restrict__ bl1,
                                             const float* __restrict__ Wl2,
                                             const float* __restrict__ bl2,
                                             float* __restrict__ out) {
    int d = blockIdx.x;
    int lane = threadIdx.x;
    int sub = lane >> 4;
    int l16 = lane & 15;
    int lo = rowstart[d], hi = rowstart[d + 1];
    if (lo >= hi) return;

    // v fragment (elements l16*8 .. +7) plus bl1
    uint4 vv = *(const uint4*)((const uint*)(v + (size_t)d * H) + l16 * 4);
    float4 ba = *(const float4*)(bl1 + l16 * 8);
    float4 bb = *(const float4*)(bl1 + l16 * 8 + 4);
    float vf0 = bflo(vv.x) + ba.x, vf1 = bfhi(vv.x) + ba.y;
    float vf2 = bflo(vv.y) + ba.z, vf3 = bfhi(vv.y) + ba.w;
    float vf4 = bflo(vv.z) + bb.x, vf5 = bfhi(vv.z) + bb.y;
    float vf6 = bflo(vv.w) + bb.z, vf7 = bfhi(vv.w) + bb.w;
    // Wl2 rows j=l16*8..+7, 2 cols each: wK.{x,y}=row j0+2K cols 0,1; wK.{z,w}=row j0+2K+1
    float4 w0 = *(const float4*)(Wl2 + l16 * 16);
    float4 w1 = *(const float4*)(Wl2 + l16 * 16 + 4);
    float4 w2 = *(const float4*)(Wl2 + l16 * 16 + 8);
    float4 w3 = *(const float4*)(Wl2 + l16 * 16 + 12);
    float b20 = bl2[0], b21 = bl2[1];

    for (int idx = lo + sub; idx < hi; idx += 4) {
        int2 e = csr2[idx];
        uint4 uu = *(const uint4*)((const uint*)(u + (size_t)e.x * H) + l16 * 4);
        float h0 = fmaxf(bflo(uu.x) + vf0, 0.f);
        float h1 = fmaxf(bfhi(uu.x) + vf1, 0.f);
        float h2 = fmaxf(bflo(uu.y) + vf2, 0.f);
        float h3 = fmaxf(bfhi(uu.y) + vf3, 0.f);
        float h4 = fmaxf(bflo(uu.z) + vf4, 0.f);
        float h5 = fmaxf(bfhi(uu.z) + vf5, 0.f);
        float h6 = fmaxf(bflo(uu.w) + vf6, 0.f);
        float h7 = fmaxf(bfhi(uu.w) + vf7, 0.f);
        float p0 = h0 * w0.x + h1 * w0.z + h2 * w1.x + h3 * w1.z
                 + h4 * w2.x + h5 * w2.z + h6 * w3.x + h7 * w3.z;
        float p1 = h0 * w0.y + h1 * w0.w + h2 * w1.y + h3 * w1.w
                 + h4 * w2.y + h5 * w2.w + h6 * w3.y + h7 * w3.w;
#pragma unroll
        for (int m = 1; m < 16; m <<= 1) {
            p0 += __shfl_xor(p0, m, 64);
            p1 += __shfl_xor(p1, m, 64);
        }
        if (l16 == 0) {
            float2 o;
            o.x = fmaxf(p0 + b20, 0.f);
            o.y = fmaxf(p1 + b21, 0.f);
            *(float2*)(out + (size_t)e.y * 2) = o;
        }
    }
}

extern "C" void kernel_launch(void* const* d_in, const int* in_sizes, int n_in,
                              void* d_out, int out_size, void* d_ws, size_t ws_size,
                              hipStream_t stream) {
    const float* x   = (const float*)d_in[0];
    const float* W1  = (const float*)d_in[1];
    const float* b1  = (const float*)d_in[2];
    const float* W2  = (const float*)d_in[3];
    const float* b2  = (const float*)d_in[4];
    const float* Wl1 = (const float*)d_in[5];
    const float* bl1 = (const float*)d_in[6];
    const float* Wl2 = (const float*)d_in[7];
    const float* bl2 = (const float*)d_in[8];
    const int*   ei  = (const int*)d_in[9];
    const int* src = ei;
    const int* dst = ei + NE;
    float* out = (float*)d_out;

    char* ws = (char*)d_ws;
    size_t off = 0;
    auto alloc = [&](size_t bytes) -> void* {
        void* p = ws + off;
        off = (off + bytes + 255) & ~(size_t)255;
        return p;
    };
    const size_t NP = 50048;  // padded rows (gemm tile over-read safety)
    int*    indeg    = (int*)alloc(NN * 4);
    float*  dinv     = (float*)alloc(NN * 4);
    int*    rowstart = (int*)alloc((NN + 1) * 4);
    int*    cursor   = (int*)alloc(NN * 4);
    int2*   csr2     = (int2*)alloc((size_t)NE * 8);
    float*  pf       = (float*)alloc(NP * H * 4);    // p1 then p2 (f32)
    ushort* hbf      = (ushort*)alloc(NP * H * 2);   // h1 then h2 (bf16)
    ushort* ubf      = (ushort*)alloc(NP * H * 2);
    ushort* vbf      = (ushort*)alloc(NP * H * 2);

    k_zero2<<<(NN + 255) / 256, 256, 0, stream>>>(indeg, cursor, NN);
    k_indeg<<<(NE + 255) / 256, 256, 0, stream>>>(dst, indeg);
    k_dinv<<<(NN + 255) / 256, 256, 0, stream>>>(indeg, dinv);
    k_scan<<<1, 1024, 0, stream>>>(indeg, rowstart);
    k_fill<<<(NE + 255) / 256, 256, 0, stream>>>(src, dst, rowstart, cursor, csr2);

    k_xw1<<<NN / 2, 256, 0, stream>>>(x, W1, hbf);                        // h1
    k_agg<<<NN, 64, 0, stream>>>(hbf, dinv, rowstart, csr2, b1, pf);      // p1
    k_gemm128<<<(NN + GNT - 1) / GNT, 256, 0, stream>>>(pf, W2, hbf);     // h2
    k_agg<<<NN, 64, 0, stream>>>(hbf, dinv, rowstart, csr2, b2, pf);      // p2
    k_gemm128<<<(NN + GNT - 1) / GNT, 256, 0, stream>>>(pf, Wl1, ubf);            // u
    k_gemm128<<<(NN + GNT - 1) / GNT, 256, 0, stream>>>(pf, Wl1 + 128 * H, vbf);  // v
    k_edge<<<NN, 64, 0, stream>>>(rowstart, csr2, ubf, vbf, bl1, Wl2, bl2, out);
}

// Round 3
// 373.736 us; speedup vs baseline: 1.6358x; 1.2449x over previous
//
#include <hip/hip_runtime.h>

#define NN 50000
#define NE 800000
#define F_IN 8
#define H 128
#define SCAN_NBLK ((NN + 255) / 256)   // 196

typedef unsigned int uint;
typedef unsigned short ushort;

__device__ __forceinline__ ushort f2bf(float f) {
    uint u = __float_as_uint(f);
    uint r = (u + 0x7fffu + ((u >> 16) & 1u)) >> 16;
    return (ushort)r;
}
__device__ __forceinline__ float bflo(uint u) { return __uint_as_float(u << 16); }
__device__ __forceinline__ float bfhi(uint u) { return __uint_as_float(u & 0xffff0000u); }

struct ushort4x { ushort a, b, c, d; };

__global__ void k_zero2(int* __restrict__ a, int* __restrict__ b, int n) {
    int i = blockIdx.x * blockDim.x + threadIdx.x;
    if (i < n) { a[i] = 0; b[i] = 0; }
}

__global__ void k_indeg(const int* __restrict__ dst, int* __restrict__ indeg) {
    int i = blockIdx.x * blockDim.x + threadIdx.x;
    if (i < NE) atomicAdd(&indeg[dst[i]], 1);
}

__global__ void k_dinv(const int* __restrict__ indeg, float* __restrict__ dinv) {
    int i = blockIdx.x * blockDim.x + threadIdx.x;
    if (i < NN) dinv[i] = rsqrtf((float)(indeg[i] + 1));
}

// ---- multi-block exclusive scan of indeg -> rowstart ----
__global__ __launch_bounds__(256) void k_bsum(const int* __restrict__ indeg,
                                              int* __restrict__ bsum) {
    int b = blockIdx.x;
    int i = b * 256 + threadIdx.x;
    int v = (i < NN) ? indeg[i] : 0;
#pragma unroll
    for (int m = 1; m < 64; m <<= 1) v += __shfl_xor(v, m, 64);
    __shared__ int ws[4];
    if ((threadIdx.x & 63) == 0) ws[threadIdx.x >> 6] = v;
    __syncthreads();
    if (threadIdx.x == 0) bsum[b] = ws[0] + ws[1] + ws[2] + ws[3];
}

__global__ __launch_bounds__(256) void k_bscan(const int* __restrict__ bsum,
                                               int* __restrict__ boff) {
    __shared__ int s[256];
    int t = threadIdx.x;
    s[t] = (t < SCAN_NBLK) ? bsum[t] : 0;
    __syncthreads();
    for (int off = 1; off < 256; off <<= 1) {
        int u = (t >= off) ? s[t - off] : 0;
        __syncthreads();
        s[t] += u;
        __syncthreads();
    }
    boff[t] = (t == 0) ? 0 : s[t - 1];
}

__global__ __launch_bounds__(256) void k_rowstart(const int* __restrict__ indeg,
                                                  const int* __restrict__ boff,
                                                  int* __restrict__ rowstart) {
    int b = blockIdx.x, t = threadIdx.x;
    int i = b * 256 + t;
    int v = (i < NN) ? indeg[i] : 0;
    __shared__ int s[256];
    s[t] = v;
    __syncthreads();
    for (int off = 1; off < 256; off <<= 1) {
        int u = (t >= off) ? s[t - off] : 0;
        __syncthreads();
        s[t] += u;
        __syncthreads();
    }
    if (i < NN) rowstart[i] = boff[b] + s[t] - v;
    if (i == NN - 1) rowstart[NN] = NE;
}

// CSR entries carry (src, edge_id) so the edge stage can run dst-sorted.
__global__ void k_fill(const int* __restrict__ src, const int* __restrict__ dst,
                       const int* __restrict__ rowstart, int* __restrict__ cursor,
                       int2* __restrict__ csr2) {
    int i = blockIdx.x * blockDim.x + threadIdx.x;
    if (i < NE) {
        int d = dst[i];
        int pos = atomicAdd(&cursor[d], 1);
        csr2[rowstart[d] + pos] = make_int2(src[i], i);
    }
}

// h[n][j] = sum_k x[n][k] * W1[k][j], bf16 output  (2 nodes / 256-thread block)
__global__ __launch_bounds__(256) void k_xw1(const float* __restrict__ x,
                                             const float* __restrict__ W1,
                                             ushort* __restrict__ h) {
    int t = threadIdx.x;
    int n = blockIdx.x * 2 + (t >> 7);
    int j = t & 127;
    const float* xr = x + n * F_IN;
    float acc = 0.f;
#pragma unroll
    for (int k = 0; k < F_IN; ++k) acc += xr[k] * W1[k * H + j];
    h[n * H + j] = f2bf(acc);
}

// p[n] = relu( h[n]*dinv[n]^2 + sum_{incoming s} h[s]*dinv[s]*dinv[n] + bias )
// h bf16; 64 threads/block, lane t owns columns (2t,2t+1); edge loop unrolled x2.
__global__ __launch_bounds__(64) void k_agg(const ushort* __restrict__ h,
                                            const float* __restrict__ dinv,
                                            const int* __restrict__ rowstart,
                                            const int2* __restrict__ csr2,
                                            const float* __restrict__ bias,
                                            float* __restrict__ p) {
    int n = blockIdx.x, t = threadIdx.x;
    float dn = dinv[n];
    uint us = ((const uint*)(h + (size_t)n * H))[t];
    float w0 = dn * dn;
    float ax = bflo(us) * w0;
    float ay = bfhi(us) * w0;
    int lo = rowstart[n], hi = rowstart[n + 1];
    int i = lo;
    for (; i + 1 < hi; i += 2) {
        int2 e0 = csr2[i];
        int2 e1 = csr2[i + 1];
        uint u0 = ((const uint*)(h + (size_t)e0.x * H))[t];
        uint u1 = ((const uint*)(h + (size_t)e1.x * H))[t];
        float wa = dinv[e0.x] * dn;
        float wb = dinv[e1.x] * dn;
        ax += bflo(u0) * wa + bflo(u1) * wb;
        ay += bfhi(u0) * wa + bfhi(u1) * wb;
    }
    if (i < hi) {
        int2 e0 = csr2[i];
        uint u0 = ((const uint*)(h + (size_t)e0.x * H))[t];
        float wa = dinv[e0.x] * dn;
        ax += bflo(u0) * wa;
        ay += bfhi(u0) * wa;
    }
    float2 bb = ((const float2*)bias)[t];
    float2 r;
    r.x = fmaxf(ax + bb.x, 0.f);
    r.y = fmaxf(ay + bb.y, 0.f);
    ((float2*)p)[(size_t)n * (H / 2) + t] = r;
}

// Y[.,128](bf16) = X[.,128](f32) @ W[128][128]; 32 rows / 256-thread block.
#define GNT 32
__global__ __launch_bounds__(256) void k_gemm128(const float* __restrict__ X,
                                                 const float* __restrict__ W,
                                                 ushort* __restrict__ Y) {
    __shared__ float Ws[128 * 128];
    int t = threadIdx.x;
    int base = blockIdx.x * GNT;
    for (int i = t * 4; i < 128 * 128; i += 256 * 4)
        *(float4*)&Ws[i] = *(const float4*)&W[i];
    __syncthreads();
    int jt = (t & 31) * 4;        // 4 output cols
    int nt = (t >> 5) * 4;        // 4 local rows
    float4 a0 = {0,0,0,0}, a1 = {0,0,0,0}, a2 = {0,0,0,0}, a3 = {0,0,0,0};
    const float* x0 = X + (size_t)(base + nt + 0) * H;
    const float* x1 = X + (size_t)(base + nt + 1) * H;
    const float* x2 = X + (size_t)(base + nt + 2) * H;
    const float* x3 = X + (size_t)(base + nt + 3) * H;
    for (int k0 = 0; k0 < 128; k0 += 4) {
        float4 xv0 = *(const float4*)(x0 + k0);
        float4 xv1 = *(const float4*)(x1 + k0);
        float4 xv2 = *(const float4*)(x2 + k0);
        float4 xv3 = *(const float4*)(x3 + k0);
#pragma unroll
        for (int kk = 0; kk < 4; ++kk) {
            float4 w = *(float4*)&Ws[(k0 + kk) * 128 + jt];
            float v0 = (&xv0.x)[kk], v1 = (&xv1.x)[kk], v2 = (&xv2.x)[kk], v3 = (&xv3.x)[kk];
            a0.x += v0 * w.x; a0.y += v0 * w.y; a0.z += v0 * w.z; a0.w += v0 * w.w;
            a1.x += v1 * w.x; a1.y += v1 * w.y; a1.z += v1 * w.z; a1.w += v1 * w.w;
            a2.x += v2 * w.x; a2.y += v2 * w.y; a2.z += v2 * w.z; a2.w += v2 * w.w;
            a3.x += v3 * w.x; a3.y += v3 * w.y; a3.z += v3 * w.z; a3.w += v3 * w.w;
        }
    }
    ushort4x o;
    if (base + nt + 0 < NN) {
        o.a = f2bf(a0.x); o.b = f2bf(a0.y); o.c = f2bf(a0.z); o.d = f2bf(a0.w);
        *(ushort4x*)&Y[(size_t)(base + nt + 0) * H + jt] = o;
    }
    if (base + nt + 1 < NN) {
        o.a = f2bf(a1.x); o.b = f2bf(a1.y); o.c = f2bf(a1.z); o.d = f2bf(a1.w);
        *(ushort4x*)&Y[(size_t)(base + nt + 1) * H + jt] = o;
    }
    if (base + nt + 2 < NN) {
        o.a = f2bf(a2.x); o.b = f2bf(a2.y); o.c = f2bf(a2.z); o.d = f2bf(a2.w);
        *(ushort4x*)&Y[(size_t)(base + nt + 2) * H + jt] = o;
    }
    if (base + nt + 3 < NN) {
        o.a = f2bf(a3.x); o.b = f2bf(a3.y); o.c = f2bf(a3.z); o.d = f2bf(a3.w);
        *(ushort4x*)&Y[(size_t)(base + nt + 3) * H + jt] = o;
    }
}

// Dst-sorted fused edge stage. One wave per destination node.
__global__ __launch_bounds__(64) void k_edge(const int* __restrict__ rowstart,
                                             const int2* __restrict__ csr2,
                                             const ushort* __restrict__ u,
                                             const ushort* __restrict__ v,
                                             const float* __restrict__ bl1,
                                             const float* __restrict__ Wl2,
                                             const float* __restrict__ bl2,
                                             float* __restrict__ out) {
    int d = blockIdx.x;
    int lane = threadIdx.x;
    int sub = lane >> 4;
    int l16 = lane & 15;
    int lo = rowstart[d], hi = rowstart[d + 1];
    if (lo >= hi) return;

    uint4 vv = *(const uint4*)((const uint*)(v + (size_t)d * H) + l16 * 4);
    float4 ba = *(const float4*)(bl1 + l16 * 8);
    float4 bb = *(const float4*)(bl1 + l16 * 8 + 4);
    float vf0 = bflo(vv.x) + ba.x, vf1 = bfhi(vv.x) + ba.y;
    float vf2 = bflo(vv.y) + ba.z, vf3 = bfhi(vv.y) + ba.w;
    float vf4 = bflo(vv.z) + bb.x, vf5 = bfhi(vv.z) + bb.y;
    float vf6 = bflo(vv.w) + bb.z, vf7 = bfhi(vv.w) + bb.w;
    float4 w0 = *(const float4*)(Wl2 + l16 * 16);
    float4 w1 = *(const float4*)(Wl2 + l16 * 16 + 4);
    float4 w2 = *(const float4*)(Wl2 + l16 * 16 + 8);
    float4 w3 = *(const float4*)(Wl2 + l16 * 16 + 12);
    float b20 = bl2[0], b21 = bl2[1];

    for (int idx = lo + sub; idx < hi; idx += 4) {
        int2 e = csr2[idx];
        uint4 uu = *(const uint4*)((const uint*)(u + (size_t)e.x * H) + l16 * 4);
        float h0 = fmaxf(bflo(uu.x) + vf0, 0.f);
        float h1 = fmaxf(bfhi(uu.x) + vf1, 0.f);
        float h2 = fmaxf(bflo(uu.y) + vf2, 0.f);
        float h3 = fmaxf(bfhi(uu.y) + vf3, 0.f);
        float h4 = fmaxf(bflo(uu.z) + vf4, 0.f);
        float h5 = fmaxf(bfhi(uu.z) + vf5, 0.f);
        float h6 = fmaxf(bflo(uu.w) + vf6, 0.f);
        float h7 = fmaxf(bfhi(uu.w) + vf7, 0.f);
        float p0 = h0 * w0.x + h1 * w0.z + h2 * w1.x + h3 * w1.z
                 + h4 * w2.x + h5 * w2.z + h6 * w3.x + h7 * w3.z;
        float p1 = h0 * w0.y + h1 * w0.w + h2 * w1.y + h3 * w1.w
                 + h4 * w2.y + h5 * w2.w + h6 * w3.y + h7 * w3.w;
#pragma unroll
        for (int m = 1; m < 16; m <<= 1) {
            p0 += __shfl_xor(p0, m, 64);
            p1 += __shfl_xor(p1, m, 64);
        }
        if (l16 == 0) {
            float2 o;
            o.x = fmaxf(p0 + b20, 0.f);
            o.y = fmaxf(p1 + b21, 0.f);
            *(float2*)(out + (size_t)e.y * 2) = o;
        }
    }
}

extern "C" void kernel_launch(void* const* d_in, const int* in_sizes, int n_in,
                              void* d_out, int out_size, void* d_ws, size_t ws_size,
                              hipStream_t stream) {
    const float* x   = (const float*)d_in[0];
    const float* W1  = (const float*)d_in[1];
    const float* b1  = (const float*)d_in[2];
    const float* W2  = (const float*)d_in[3];
    const float* b2  = (const float*)d_in[4];
    const float* Wl1 = (const float*)d_in[5];
    const float* bl1 = (const float*)d_in[6];
    const float* Wl2 = (const float*)d_in[7];
    const float* bl2 = (const float*)d_in[8];
    const int*   ei  = (const int*)d_in[9];
    const int* src = ei;
    const int* dst = ei + NE;
    float* out = (float*)d_out;

    char* ws = (char*)d_ws;
    size_t off = 0;
    auto alloc = [&](size_t bytes) -> void* {
        void* p = ws + off;
        off = (off + bytes + 255) & ~(size_t)255;
        return p;
    };
    const size_t NP = 50048;  // padded rows (gemm tile over-read safety)
    int*    indeg    = (int*)alloc(NN * 4);
    float*  dinv     = (float*)alloc(NN * 4);
    int*    rowstart = (int*)alloc((NN + 1) * 4);
    int*    cursor   = (int*)alloc(NN * 4);
    int*    bsum     = (int*)alloc(256 * 4);
    int*    boff     = (int*)alloc(256 * 4);
    int2*   csr2     = (int2*)alloc((size_t)NE * 8);
    float*  pf       = (float*)alloc(NP * H * 4);    // p1 then p2 (f32)
    ushort* hbf      = (ushort*)alloc(NP * H * 2);   // h1 then h2 (bf16)
    ushort* ubf      = (ushort*)alloc(NP * H * 2);
    ushort* vbf      = (ushort*)alloc(NP * H * 2);

    k_zero2<<<(NN + 255) / 256, 256, 0, stream>>>(indeg, cursor, NN);
    k_indeg<<<(NE + 255) / 256, 256, 0, stream>>>(dst, indeg);
    k_dinv<<<(NN + 255) / 256, 256, 0, stream>>>(indeg, dinv);
    k_bsum<<<SCAN_NBLK, 256, 0, stream>>>(indeg, bsum);
    k_bscan<<<1, 256, 0, stream>>>(bsum, boff);
    k_rowstart<<<SCAN_NBLK, 256, 0, stream>>>(indeg, boff, rowstart);
    k_fill<<<(NE + 255) / 256, 256, 0, stream>>>(src, dst, rowstart, cursor, csr2);

    k_xw1<<<NN / 2, 256, 0, stream>>>(x, W1, hbf);                        // h1
    k_agg<<<NN, 64, 0, stream>>>(hbf, dinv, rowstart, csr2, b1, pf);      // p1
    k_gemm128<<<(NN + GNT - 1) / GNT, 256, 0, stream>>>(pf, W2, hbf);     // h2
    k_agg<<<NN, 64, 0, stream>>>(hbf, dinv, rowstart, csr2, b2, pf);      // p2
    k_gemm128<<<(NN + GNT - 1) / GNT, 256, 0, stream>>>(pf, Wl1, ubf);            // u
    k_gemm128<<<(NN + GNT - 1) / GNT, 256, 0, stream>>>(pf, Wl1 + 128 * H, vbf);  // v
    k_edge<<<NN, 64, 0, stream>>>(rowstart, csr2, ubf, vbf, bl1, Wl2, bl2, out);
}